// Round 2
// baseline (141.094 us; speedup 1.0000x reference)
//
#include <hip/hip_runtime.h>

#define NCAND 40
#define NC2   1600
#define NP    256

// ---------------- Kernel 1: candidate patch distances (float32, numpy-exact) ----
// Replicates np.float32 semantics of:
//   diff = patches - sample; dist = sqrt(sum(diff*diff, axis=(0,3,4)))
// numpy pairwise summation over the contiguous 256-elem (a,b) run per channel:
//   256 -> two 128-blocks; each 128-block uses 8 interleaved accumulators
//   combined ((r0+r1)+(r2+r3))+((r4+r5)+(r6+r7)); channel sums added
//   sequentially. All ops via __f*_rn intrinsics to block fp-contract=fast.
__global__ void k_dist(const float* __restrict__ feat0,
                       const int* __restrict__ loc,
                       float* __restrict__ dist) {
    __shared__ float smp[3 * 16 * 16];
    const int lh = loc[0], lw = loc[1];
    for (int t = threadIdx.x; t < 768; t += blockDim.x) {
        int c = t >> 8;
        int rem = t & 255;
        int a = rem >> 4;
        int b = rem & 15;
        smp[t] = feat0[c * 65536 + (lh - 8 + a) * 256 + (lw - 8 + b)];
    }
    __syncthreads();

    int cand = blockIdx.x * blockDim.x + threadIdx.x;
    if (cand >= NC2) return;
    const int i = cand / NCAND;
    const int j = cand % NCAND;
    const int base_h = lh - 28 + i;
    const int base_w = lw - 28 + j;

    float tot = 0.0f;
    for (int c = 0; c < 3; ++c) {
        const float* fp = feat0 + c * 65536;
        const float* sc = smp + c * 256;
        float half_sum[2];
#pragma unroll
        for (int h = 0; h < 2; ++h) {
            float r[8];
#pragma unroll
            for (int k = 0; k < 16; ++k) {
#pragma unroll
                for (int u = 0; u < 8; ++u) {
                    const int idx = h * 128 + k * 8 + u;   // flat a*16+b
                    const int a = idx >> 4;
                    const int b = idx & 15;
                    float v = fp[(base_h + a) * 256 + base_w + b];
                    float d = __fsub_rn(v, sc[idx]);
                    float sq = __fmul_rn(d, d);
                    r[u] = (k == 0) ? sq : __fadd_rn(r[u], sq);
                }
            }
            float t01 = __fadd_rn(r[0], r[1]);
            float t23 = __fadd_rn(r[2], r[3]);
            float t45 = __fadd_rn(r[4], r[5]);
            float t67 = __fadd_rn(r[6], r[7]);
            half_sum[h] = __fadd_rn(__fadd_rn(t01, t23), __fadd_rn(t45, t67));
        }
        float pc = __fadd_rn(half_sum[0], half_sum[1]);
        tot = (c == 0) ? pc : __fadd_rn(tot, pc);
    }
    dist[cand] = __fsqrt_rn(tot);   // f32 sqrt: can merge ties exactly like np
}

// ---------------- Kernel 2: exact rank selection (top-256 ascending) --------
// rank(t) = #{k : d[k] < d[t] || (d[k]==d[t] && k < t)} -- strict total order,
// reproduces lax.top_k / stable-argsort tie-breaking (lower index first).
__global__ void k_rank(const float* __restrict__ dist,
                       const int* __restrict__ loc,
                       int* __restrict__ hw,
                       float* __restrict__ out_ids) {
    int t = blockIdx.x * blockDim.x + threadIdx.x;
    if (t >= NC2) return;
    float dt = dist[t];
    int rank = 0;
    for (int k = 0; k < NC2; ++k) {
        float dk = dist[k];
        rank += (dk < dt || (dk == dt && k < t)) ? 1 : 0;
    }
    if (rank < NP) {
        int lh = loc[0], lw = loc[1];
        int h = lh - 20 + t / NCAND;
        int w = lw - 20 + t % NCAND;
        hw[rank * 2]     = h;
        hw[rank * 2 + 1] = w;
        out_ids[rank * 2]     = (float)h;
        out_ids[rank * 2 + 1] = (float)w;
    }
}

// ---------------- Kernel 3: gather + L2-normalize ---------------------------
__global__ void k_gather(const float* __restrict__ f0,
                         const float* __restrict__ f1,
                         const float* __restrict__ f2,
                         const float* __restrict__ f3,
                         const int* __restrict__ hw,
                         float* __restrict__ out) {
    const int r = blockIdx.x & 255;
    const int f = blockIdx.x >> 8;

    const float* src;
    int C, H;
    long off;
    if (f == 0)      { src = f0; C = 3;    H = 256; off = 0; }
    else if (f == 1) { src = f1; C = 256;  H = 256; off = 768; }
    else if (f == 2) { src = f2; C = 512;  H = 128; off = 768 + 65536; }
    else             { src = f3; C = 1024; H = 64;  off = 768 + 65536 + 131072; }
    const int W = H;

    const int h = hw[r * 2], w = hw[r * 2 + 1];
    const int hh = (h * H) / 256;
    const int ww = (w * H) / 256;
    const long base = (long)hh * W + ww;
    const long HW = (long)H * W;

    float x[4];
    double acc = 0.0;
    int n = 0;
    for (int c = threadIdx.x; c < C; c += 256) {
        float v = src[(long)c * HW + base];
        x[n++] = v;
        acc = fma((double)v, (double)v, acc);
    }

    for (int o = 32; o > 0; o >>= 1) acc += __shfl_down(acc, o, 64);
    __shared__ double red[4];
    const int lane = threadIdx.x & 63;
    const int wid  = threadIdx.x >> 6;
    if (lane == 0) red[wid] = acc;
    __syncthreads();
    const double total = red[0] + red[1] + red[2] + red[3];
    const float scale = (float)(1.0 / (sqrt(total) + 1e-7));

    n = 0;
    for (int c = threadIdx.x; c < C; c += 256) {
        out[off + (long)r * C + c] = x[n++] * scale;
    }
}

extern "C" void kernel_launch(void* const* d_in, const int* in_sizes, int n_in,
                              void* d_out, int out_size, void* d_ws, size_t ws_size,
                              hipStream_t stream) {
    const float* feat0 = (const float*)d_in[0];
    const float* feat1 = (const float*)d_in[1];
    const float* feat2 = (const float*)d_in[2];
    const float* feat3 = (const float*)d_in[3];
    const int*   loc   = (const int*)d_in[4];
    float* out = (float*)d_out;

    float* dist = (float*)d_ws;                                  // 1600 floats
    int* hw = (int*)((char*)d_ws + NC2 * sizeof(float));         // 512 ints

    float* out_ids = out + 768 + 65536 + 131072 + 262144;        // offset 459520

    k_dist<<<(NC2 + 255) / 256, 256, 0, stream>>>(feat0, loc, dist);
    k_rank<<<(NC2 + 255) / 256, 256, 0, stream>>>(dist, loc, hw, out_ids);
    k_gather<<<4 * NP, 256, 0, stream>>>(feat0, feat1, feat2, feat3, hw, out);
}

// Round 3
// 57.654 us; speedup vs baseline: 2.4472x; 2.4472x over previous
//
#include <hip/hip_runtime.h>

#define NCAND 40
#define NC2   1600
#define NP    256

// ---------------- Kernel 1: candidate patch distances (float32, numpy-exact) ----
// Wave-per-candidate. Lane = c*16 + h*8 + u (lanes 0..47 active, 48..63 compute
// harmless duplicates). Each lane runs one 16-step sequential accumulator chain
// r[u]; the numpy pairwise tree ((r0+r1)+(r2+r3))+((r4+r5)+(r6+r7)) is realized
// bit-exactly by a shfl_xor butterfly (IEEE add commutes), xor8 merges halves,
// explicit shfl from lanes 16/32 gives the sequential channel sum (p0+p1)+p2.
// All ops via __f*_rn intrinsics to block fp-contract=fast.
__global__ void k_dist(const float* __restrict__ feat0,
                       const int* __restrict__ loc,
                       float* __restrict__ dist) {
    __shared__ float smp[3 * 16 * 16];
    const int lh = loc[0], lw = loc[1];
    for (int t = threadIdx.x; t < 768; t += 256) {
        int c = t >> 8;
        int rem = t & 255;
        int a = rem >> 4;
        int b = rem & 15;
        smp[t] = feat0[c * 65536 + (lh - 8 + a) * 256 + (lw - 8 + b)];
    }
    __syncthreads();

    const int wid  = threadIdx.x >> 6;
    const int lane = threadIdx.x & 63;
    const int cand = blockIdx.x * 4 + wid;          // 400 blocks * 4 waves = 1600
    const int i = cand / NCAND;
    const int j = cand % NCAND;
    const int base_h = lh - 28 + i;
    const int base_w = lw - 28 + j;

    int c = lane >> 4;
    if (c > 2) c = 0;                               // lanes 48..63: duplicate c=0
    const int h = (lane >> 3) & 1;
    const int u = lane & 7;
    const float* fp = feat0 + c * 65536;
    const float* sc = smp + c * 256;

    float r = 0.0f;
#pragma unroll
    for (int k = 0; k < 16; ++k) {
        const int idx = h * 128 + k * 8 + u;        // flat a*16+b within the patch
        const int a = idx >> 4;
        const int b = idx & 15;
        float v = fp[(base_h + a) * 256 + base_w + b];
        float d = __fsub_rn(v, sc[idx]);
        float sq = __fmul_rn(d, d);
        r = (k == 0) ? sq : __fadd_rn(r, sq);
    }
    // pairwise tree over u (bit-exact butterfly), then halves (h bit)
    r = __fadd_rn(r, __shfl_xor(r, 1, 64));
    r = __fadd_rn(r, __shfl_xor(r, 2, 64));
    r = __fadd_rn(r, __shfl_xor(r, 4, 64));
    r = __fadd_rn(r, __shfl_xor(r, 8, 64));
    // sequential channel combine (p0+p1)+p2, valid on lane 0
    float p1 = __shfl(r, 16, 64);
    float p2 = __shfl(r, 32, 64);
    float tot = __fadd_rn(__fadd_rn(r, p1), p2);
    if (lane == 0) dist[cand] = __fsqrt_rn(tot);
}

// ---------------- Kernel 2: exact rank selection (top-256 ascending) --------
// rank(t) = #{k : d[k] < d[t] || (d[k]==d[t] && k < t)} -- strict total order,
// reproduces top_k tie-breaking. dist[] staged in LDS; float4 scan with
// same-address broadcast (conflict-free).
__global__ void k_rank(const float* __restrict__ dist,
                       const int* __restrict__ loc,
                       int* __restrict__ hw,
                       float* __restrict__ out_ids) {
    __shared__ __align__(16) float ds[NC2];
    for (int k = threadIdx.x; k < NC2; k += 256) ds[k] = dist[k];
    __syncthreads();

    const int t = blockIdx.x * 256 + threadIdx.x;
    if (t >= NC2) return;
    const float dt = ds[t];
    int rank = 0;
    const float4* d4 = (const float4*)ds;
#pragma unroll 4
    for (int k4 = 0; k4 < NC2 / 4; ++k4) {
        float4 v = d4[k4];
        int kb = k4 * 4;
        rank += (v.x < dt || (v.x == dt && kb + 0 < t)) ? 1 : 0;
        rank += (v.y < dt || (v.y == dt && kb + 1 < t)) ? 1 : 0;
        rank += (v.z < dt || (v.z == dt && kb + 2 < t)) ? 1 : 0;
        rank += (v.w < dt || (v.w == dt && kb + 3 < t)) ? 1 : 0;
    }
    if (rank < NP) {
        int lh = loc[0], lw = loc[1];
        int h = lh - 20 + t / NCAND;
        int w = lw - 20 + t % NCAND;
        hw[rank * 2]     = h;
        hw[rank * 2 + 1] = w;
        out_ids[rank * 2]     = (float)h;
        out_ids[rank * 2 + 1] = (float)w;
    }
}

// ---------------- Kernel 3: gather + L2-normalize ---------------------------
__global__ void k_gather(const float* __restrict__ f0,
                         const float* __restrict__ f1,
                         const float* __restrict__ f2,
                         const float* __restrict__ f3,
                         const int* __restrict__ hw,
                         float* __restrict__ out) {
    const int r = blockIdx.x & 255;
    const int f = blockIdx.x >> 8;

    const float* src;
    int C, H;
    long off;
    if (f == 0)      { src = f0; C = 3;    H = 256; off = 0; }
    else if (f == 1) { src = f1; C = 256;  H = 256; off = 768; }
    else if (f == 2) { src = f2; C = 512;  H = 128; off = 768 + 65536; }
    else             { src = f3; C = 1024; H = 64;  off = 768 + 65536 + 131072; }
    const int W = H;

    const int h = hw[r * 2], w = hw[r * 2 + 1];
    const int hh = (h * H) / 256;
    const int ww = (w * H) / 256;
    const long base = (long)hh * W + ww;
    const long HW = (long)H * W;

    float x[4];
    double acc = 0.0;
    int n = 0;
    for (int c = threadIdx.x; c < C; c += 256) {
        float v = src[(long)c * HW + base];
        x[n++] = v;
        acc = fma((double)v, (double)v, acc);
    }

    for (int o = 32; o > 0; o >>= 1) acc += __shfl_down(acc, o, 64);
    __shared__ double red[4];
    const int lane = threadIdx.x & 63;
    const int wid  = threadIdx.x >> 6;
    if (lane == 0) red[wid] = acc;
    __syncthreads();
    const double total = red[0] + red[1] + red[2] + red[3];
    const float scale = (float)(1.0 / (sqrt(total) + 1e-7));

    n = 0;
    for (int c = threadIdx.x; c < C; c += 256) {
        out[off + (long)r * C + c] = x[n++] * scale;
    }
}

extern "C" void kernel_launch(void* const* d_in, const int* in_sizes, int n_in,
                              void* d_out, int out_size, void* d_ws, size_t ws_size,
                              hipStream_t stream) {
    const float* feat0 = (const float*)d_in[0];
    const float* feat1 = (const float*)d_in[1];
    const float* feat2 = (const float*)d_in[2];
    const float* feat3 = (const float*)d_in[3];
    const int*   loc   = (const int*)d_in[4];
    float* out = (float*)d_out;

    float* dist = (float*)d_ws;                              // 1600 floats
    int* hw = (int*)((char*)d_ws + NC2 * sizeof(float));     // 512 ints

    float* out_ids = out + 768 + 65536 + 131072 + 262144;    // offset 459520

    k_dist<<<NC2 / 4, 256, 0, stream>>>(feat0, loc, dist);
    k_rank<<<(NC2 + 255) / 256, 256, 0, stream>>>(dist, loc, hw, out_ids);
    k_gather<<<4 * NP, 256, 0, stream>>>(feat0, feat1, feat2, feat3, hw, out);
}

// Round 4
// 18.742 us; speedup vs baseline: 7.5280x; 3.0761x over previous
//
#include <hip/hip_runtime.h>

#define NCAND 40
#define NC2   1600
#define NP    256

// ---------------- Kernel 1: candidate patch distances (float32, numpy-exact) ----
// Wave-per-candidate. Lane = c*16 + h*8 + u (lanes 0..47 active, 48..63 compute
// harmless duplicates). Each lane runs one 16-step sequential accumulator chain
// r[u]; the numpy pairwise tree ((r0+r1)+(r2+r3))+((r4+r5)+(r6+r7)) is realized
// bit-exactly by a shfl_xor butterfly (IEEE add commutes), xor8 merges halves,
// explicit shfl from lanes 16/32 gives the sequential channel sum (p0+p1)+p2.
// All ops via __f*_rn intrinsics to block fp-contract=fast.
__global__ void k_dist(const float* __restrict__ feat0,
                       const int* __restrict__ loc,
                       float* __restrict__ dist) {
    __shared__ float smp[3 * 16 * 16];
    const int lh = loc[0], lw = loc[1];
    for (int t = threadIdx.x; t < 768; t += 256) {
        int c = t >> 8;
        int rem = t & 255;
        int a = rem >> 4;
        int b = rem & 15;
        smp[t] = feat0[c * 65536 + (lh - 8 + a) * 256 + (lw - 8 + b)];
    }
    __syncthreads();

    const int wid  = threadIdx.x >> 6;
    const int lane = threadIdx.x & 63;
    const int cand = blockIdx.x * 4 + wid;          // 400 blocks * 4 waves = 1600
    const int i = cand / NCAND;
    const int j = cand % NCAND;
    const int base_h = lh - 28 + i;
    const int base_w = lw - 28 + j;

    int c = lane >> 4;
    if (c > 2) c = 0;                               // lanes 48..63: duplicate c=0
    const int h = (lane >> 3) & 1;
    const int u = lane & 7;
    const float* fp = feat0 + c * 65536;
    const float* sc = smp + c * 256;

    float r = 0.0f;
#pragma unroll
    for (int k = 0; k < 16; ++k) {
        const int idx = h * 128 + k * 8 + u;        // flat a*16+b within the patch
        const int a = idx >> 4;
        const int b = idx & 15;
        float v = fp[(base_h + a) * 256 + base_w + b];
        float d = __fsub_rn(v, sc[idx]);
        float sq = __fmul_rn(d, d);
        r = (k == 0) ? sq : __fadd_rn(r, sq);
    }
    // pairwise tree over u (bit-exact butterfly), then halves (h bit)
    r = __fadd_rn(r, __shfl_xor(r, 1, 64));
    r = __fadd_rn(r, __shfl_xor(r, 2, 64));
    r = __fadd_rn(r, __shfl_xor(r, 4, 64));
    r = __fadd_rn(r, __shfl_xor(r, 8, 64));
    // sequential channel combine (p0+p1)+p2, valid on lane 0
    float p1 = __shfl(r, 16, 64);
    float p2 = __shfl(r, 32, 64);
    float tot = __fadd_rn(__fadd_rn(r, p1), p2);
    if (lane == 0) dist[cand] = __fsqrt_rn(tot);
}

// ---------------- Kernel 2: exact rank selection (top-256 ascending) --------
// Wave-per-candidate: wave t computes rank(t) = #{k : d[k]<d[t] || (d[k]==d[t]
// && k<t)} with lane l scanning k = l + 64*m (25 steps), then a shfl_xor
// integer reduce. Same strict total order as before -- bit-identical result.
__global__ void k_rank(const float* __restrict__ dist,
                       const int* __restrict__ loc,
                       int* __restrict__ hw,
                       float* __restrict__ out_ids) {
    __shared__ float ds[NC2];
    for (int k = threadIdx.x; k < NC2; k += 256) ds[k] = dist[k];
    __syncthreads();

    const int wid  = threadIdx.x >> 6;
    const int lane = threadIdx.x & 63;
    const int t = blockIdx.x * 4 + wid;             // 400 blocks * 4 waves = 1600
    const float dt = ds[t];
    int rank = 0;
#pragma unroll
    for (int m = 0; m < NC2 / 64; ++m) {
        const int k = lane + (m << 6);
        const float dk = ds[k];
        rank += (dk < dt || (dk == dt && k < t)) ? 1 : 0;
    }
    rank += __shfl_xor(rank, 1, 64);
    rank += __shfl_xor(rank, 2, 64);
    rank += __shfl_xor(rank, 4, 64);
    rank += __shfl_xor(rank, 8, 64);
    rank += __shfl_xor(rank, 16, 64);
    rank += __shfl_xor(rank, 32, 64);

    if (lane == 0 && rank < NP) {
        const int lh = loc[0], lw = loc[1];
        const int h = lh - 20 + t / NCAND;
        const int w = lw - 20 + t % NCAND;
        hw[rank * 2]     = h;
        hw[rank * 2 + 1] = w;
        out_ids[rank * 2]     = (float)h;
        out_ids[rank * 2 + 1] = (float)w;
    }
}

// ---------------- Kernel 3: gather + L2-normalize ---------------------------
__global__ void k_gather(const float* __restrict__ f0,
                         const float* __restrict__ f1,
                         const float* __restrict__ f2,
                         const float* __restrict__ f3,
                         const int* __restrict__ hw,
                         float* __restrict__ out) {
    const int r = blockIdx.x & 255;
    const int f = blockIdx.x >> 8;

    const float* src;
    int C, H;
    long off;
    if (f == 0)      { src = f0; C = 3;    H = 256; off = 0; }
    else if (f == 1) { src = f1; C = 256;  H = 256; off = 768; }
    else if (f == 2) { src = f2; C = 512;  H = 128; off = 768 + 65536; }
    else             { src = f3; C = 1024; H = 64;  off = 768 + 65536 + 131072; }
    const int W = H;

    const int h = hw[r * 2], w = hw[r * 2 + 1];
    const int hh = (h * H) / 256;
    const int ww = (w * H) / 256;
    const long base = (long)hh * W + ww;
    const long HW = (long)H * W;

    float x[4];
    double acc = 0.0;
    int n = 0;
    for (int c = threadIdx.x; c < C; c += 256) {
        float v = src[(long)c * HW + base];
        x[n++] = v;
        acc = fma((double)v, (double)v, acc);
    }

    for (int o = 32; o > 0; o >>= 1) acc += __shfl_down(acc, o, 64);
    __shared__ double red[4];
    const int lane = threadIdx.x & 63;
    const int wid  = threadIdx.x >> 6;
    if (lane == 0) red[wid] = acc;
    __syncthreads();
    const double total = red[0] + red[1] + red[2] + red[3];
    const float scale = (float)(1.0 / (sqrt(total) + 1e-7));

    n = 0;
    for (int c = threadIdx.x; c < C; c += 256) {
        out[off + (long)r * C + c] = x[n++] * scale;
    }
}

extern "C" void kernel_launch(void* const* d_in, const int* in_sizes, int n_in,
                              void* d_out, int out_size, void* d_ws, size_t ws_size,
                              hipStream_t stream) {
    const float* feat0 = (const float*)d_in[0];
    const float* feat1 = (const float*)d_in[1];
    const float* feat2 = (const float*)d_in[2];
    const float* feat3 = (const float*)d_in[3];
    const int*   loc   = (const int*)d_in[4];
    float* out = (float*)d_out;

    float* dist = (float*)d_ws;                              // 1600 floats
    int* hw = (int*)((char*)d_ws + NC2 * sizeof(float));     // 512 ints

    float* out_ids = out + 768 + 65536 + 131072 + 262144;    // offset 459520

    k_dist<<<NC2 / 4, 256, 0, stream>>>(feat0, loc, dist);
    k_rank<<<NC2 / 4, 256, 0, stream>>>(dist, loc, hw, out_ids);
    k_gather<<<4 * NP, 256, 0, stream>>>(feat0, feat1, feat2, feat3, hw, out);
}